// Round 11
// baseline (846.142 us; speedup 1.0000x reference)
//
#include <hip/hip_runtime.h>
#include <math.h>

// SinkhornSort: P = diag(u) exp(-D) diag(v); u=1/(Kv), v=1/(K^T u), v0=1.
// Row ranking depends only on s_ij = log(v_j) - D_ij -> never materialize P.
// 3 iterations suffice (truncation ~1e-8 << shared fp32 noise ~1e-7; measured
// absmax==0 at 6, 4, 3 iters). Output = zero-fill + scatter 32 ones/row.
//
// NEW: last Sinkhorn sweep emits per-row candidate lists {col, D_ij} for all
// t = exp(-D)*v >= max_row(t) * e^-1.85 (monotone proxy of the final score;
// final lv differs from sweep lv by <1e-6 vs ~0.1 margins). Select then ranks
// candidates exactly in fp64 (jax tie rule) without re-reading D. Rows with
// cnt<48 or cnt>CAP fall back to the full-row histogram path.

#define NN 8192
#define NITER_RUN 3
#define TOPK 32
#define CAP 576
#define THRF 0.15723717f   // e^-1.85

typedef float nf4 __attribute__((ext_vector_type(4)));

__device__ __forceinline__ unsigned fkey(float f) {
    unsigned b = __float_as_uint(f);
    return (b & 0x80000000u) ? ~b : (b | 0x80000000u);
}
__device__ __forceinline__ float fkeyinv(unsigned k) {
    unsigned b = (k & 0x80000000u) ? (k & 0x7FFFFFFFu) : ~k;
    return __uint_as_float(b);
}

// ---------------- zero-fill output (non-temporal; also inits gkeys) ----------------
__global__ __launch_bounds__(256)
void fill_zero(float* __restrict__ out, unsigned* __restrict__ gkeys)
{
    if (blockIdx.x == 0 && threadIdx.x == 0) { gkeys[0] = 0xFFFFFFFFu; gkeys[1] = 0u; }
    nf4* __restrict__ o4 = (nf4*)out;
    const long base = (long)blockIdx.x * 2048 + threadIdx.x;
    nf4 z = { 0.f, 0.f, 0.f, 0.f };
#pragma unroll
    for (int c = 0; c < 8; ++c)
        __builtin_nontemporal_store(z, &o4[base + (long)c * 256]);
}

// ---------------- lean Sinkhorn iteration (non-last) ----------------
constexpr int IT_T = 512;

__global__ __launch_bounds__(IT_T, 4)
void sinkhorn_iter(const float4* __restrict__ D4, const float4* __restrict__ v4,
                   float4* __restrict__ part4, int rowsPerWg, int first)
{
    const int t = threadIdx.x;
    const int wave = t >> 6, lane = t & 63;
    __shared__ float wred[2][IT_T / 64];

    float4 vreg[4], cacc[4];
#pragma unroll
    for (int c = 0; c < 4; ++c) {
        vreg[c] = first ? make_float4(1.f, 1.f, 1.f, 1.f) : v4[c * IT_T + t];
        cacc[c] = make_float4(0.f, 0.f, 0.f, 0.f);
    }

    const long rowBase = (long)blockIdx.x * rowsPerWg;
    for (int r = 0; r < rowsPerWg; r += 2) {
        float4 ev[2][4];
#pragma unroll
        for (int rr = 0; rr < 2; ++rr) {
            const float4* __restrict__ Dr = D4 + (rowBase + r + rr) * (long)(NN / 4);
            float rs = 0.f;
#pragma unroll
            for (int c = 0; c < 4; ++c) {
                float4 d = Dr[c * IT_T + t];
                float4 e;
                e.x = __expf(-d.x); e.y = __expf(-d.y);
                e.z = __expf(-d.z); e.w = __expf(-d.w);
                ev[rr][c] = e;
                rs += e.x * vreg[c].x + e.y * vreg[c].y
                    + e.z * vreg[c].z + e.w * vreg[c].w;
            }
#pragma unroll
            for (int o = 32; o >= 1; o >>= 1) rs += __shfl_down(rs, o, 64);
            if (lane == 0) wred[rr][wave] = rs;
        }
        __syncthreads();
        float tot0 = 0.f, tot1 = 0.f;
#pragma unroll
        for (int w = 0; w < IT_T / 64; ++w) { tot0 += wred[0][w]; tot1 += wred[1][w]; }
        const float u0 = 1.0f / tot0, u1 = 1.0f / tot1;
#pragma unroll
        for (int c = 0; c < 4; ++c) {
            cacc[c].x += ev[0][c].x * u0 + ev[1][c].x * u1;
            cacc[c].y += ev[0][c].y * u0 + ev[1][c].y * u1;
            cacc[c].z += ev[0][c].z * u0 + ev[1][c].z * u1;
            cacc[c].w += ev[0][c].w * u0 + ev[1][c].w * u1;
        }
        __syncthreads();
    }

    float4* __restrict__ pr = part4 + (long)blockIdx.x * (NN / 4);
#pragma unroll
    for (int c = 0; c < 4; ++c) pr[c * IT_T + t] = cacc[c];
}

// ---------------- last Sinkhorn iteration + candidate emission ----------------
__global__ __launch_bounds__(IT_T, 4)
void sinkhorn_cand(const float4* __restrict__ D4, const float4* __restrict__ v4,
                   float4* __restrict__ part4,
                   unsigned short* __restrict__ candIdx,
                   float* __restrict__ candD,
                   unsigned* __restrict__ candCnt, int rowsPerWg)
{
    const int t = threadIdx.x;
    const int wave = t >> 6, lane = t & 63;
    __shared__ float wred[2][IT_T / 64];
    __shared__ float wmax[2][IT_T / 64];
    __shared__ unsigned rowCnt[2];

    float4 vreg[4], cacc[4];
#pragma unroll
    for (int c = 0; c < 4; ++c) {
        vreg[c] = v4[c * IT_T + t];
        cacc[c] = make_float4(0.f, 0.f, 0.f, 0.f);
    }
    if (t < 2) rowCnt[t] = 0;
    __syncthreads();

    const long rowBase = (long)blockIdx.x * rowsPerWg;
    for (int r = 0; r < rowsPerWg; r += 2) {
        float4 dv[2][4];
#pragma unroll
        for (int rr = 0; rr < 2; ++rr) {
            const float4* __restrict__ Dr = D4 + (rowBase + r + rr) * (long)(NN / 4);
            float rs = 0.f, tm = 0.f;
#pragma unroll
            for (int c = 0; c < 4; ++c) {
                float4 d = Dr[c * IT_T + t];
                dv[rr][c] = d;
                float ex = __expf(-d.x), ey = __expf(-d.y);
                float ez = __expf(-d.z), ew = __expf(-d.w);
                rs += ex * vreg[c].x + ey * vreg[c].y
                    + ez * vreg[c].z + ew * vreg[c].w;
                tm = fmaxf(tm, fmaxf(fmaxf(ex * vreg[c].x, ey * vreg[c].y),
                                     fmaxf(ez * vreg[c].z, ew * vreg[c].w)));
            }
#pragma unroll
            for (int o = 32; o >= 1; o >>= 1) {
                rs += __shfl_down(rs, o, 64);
                tm = fmaxf(tm, __shfl_down(tm, o, 64));
            }
            if (lane == 0) { wred[rr][wave] = rs; wmax[rr][wave] = tm; }
        }
        __syncthreads();
        float tot0 = 0.f, tot1 = 0.f, m0 = 0.f, m1 = 0.f;
#pragma unroll
        for (int w = 0; w < IT_T / 64; ++w) {
            tot0 += wred[0][w]; tot1 += wred[1][w];
            m0 = fmaxf(m0, wmax[0][w]); m1 = fmaxf(m1, wmax[1][w]);
        }
        const float u0 = 1.0f / tot0, u1 = 1.0f / tot1;
        const float tau0 = m0 * THRF, tau1 = m1 * THRF;

#pragma unroll
        for (int rr = 0; rr < 2; ++rr) {
            const float u = rr ? u1 : u0;
            const float tau = rr ? tau1 : tau0;
            const long rowOff = (rowBase + r + rr) * (long)CAP;

#define PROC(DD, VV, CCREF, COL)                                              \
            {                                                                 \
                float d_ = (DD);                                              \
                float e_ = __expf(-d_);                                       \
                CCREF += e_ * u;                                              \
                bool em_ = (e_ * (VV)) >= tau;                                \
                unsigned long long m_ = __ballot(em_);                        \
                if (m_) {                                                     \
                    int nb_ = (int)__popcll(m_);                              \
                    int leader_ = (int)__ffsll((unsigned long long)m_) - 1;   \
                    int base_ = 0;                                            \
                    if (lane == leader_)                                      \
                        base_ = (int)atomicAdd(&rowCnt[rr], (unsigned)nb_);   \
                    base_ = __shfl(base_, leader_, 64);                       \
                    if (em_) {                                                \
                        unsigned pos_ = (unsigned)base_ +                     \
                            (unsigned)__popcll(m_ & ((1ull << lane) - 1ull)); \
                        if (pos_ < CAP) {                                     \
                            candIdx[rowOff + pos_] = (unsigned short)(COL);   \
                            candD[rowOff + pos_] = d_;                        \
                        }                                                     \
                    }                                                         \
                }                                                             \
            }

#pragma unroll
            for (int c = 0; c < 4; ++c) {
                const int colBase = (c * IT_T + t) * 4;
                PROC(dv[rr][c].x, vreg[c].x, cacc[c].x, colBase + 0)
                PROC(dv[rr][c].y, vreg[c].y, cacc[c].y, colBase + 1)
                PROC(dv[rr][c].z, vreg[c].z, cacc[c].z, colBase + 2)
                PROC(dv[rr][c].w, vreg[c].w, cacc[c].w, colBase + 3)
            }
#undef PROC
        }
        __syncthreads();
        if (t < 2) {
            candCnt[rowBase + r + t] = rowCnt[t];
            rowCnt[t] = 0;     // reset ordered before next batch's emits by next barrier
        }
    }

    float4* __restrict__ pr = part4 + (long)blockIdx.x * (NN / 4);
#pragma unroll
    for (int c = 0; c < 4; ++c) pr[c * IT_T + t] = cacc[c];
}

// ---------------- deterministic fused column reduction ----------------
__global__ __launch_bounds__(256)
void col_reduce(const float* __restrict__ partials, int nStrips,
                float* __restrict__ v, double* __restrict__ lvd,
                float* __restrict__ lvf, unsigned* __restrict__ gkeys, int last)
{
    __shared__ double sums[8][33];
    const int jl = threadIdx.x & 31, sg = threadIdx.x >> 5;
    const int j = blockIdx.x * 32 + jl;
    double acc = 0.0;
#pragma unroll 4
    for (int s = sg; s < nStrips; s += 8)
        acc += (double)partials[(long)s * NN + j];
    sums[sg][jl] = acc;
    __syncthreads();
    if (threadIdx.x < 32) {
        double a = 0.0;
#pragma unroll
        for (int g = 0; g < 8; ++g) a += sums[g][threadIdx.x];
        int jj = blockIdx.x * 32 + threadIdx.x;
        if (last) {
            double lv = -log(a);
            lvd[jj] = lv;
            float lf = (float)lv;
            lvf[jj] = lf;
            unsigned k = fkey(lf), kmn = k, kmx = k;
#pragma unroll
            for (int o = 16; o >= 1; o >>= 1) {
                kmn = min(kmn, (unsigned)__shfl_down((int)kmn, o, 64));
                kmx = max(kmx, (unsigned)__shfl_down((int)kmx, o, 64));
            }
            if (threadIdx.x == 0) {
                atomicMin(&gkeys[0], kmn);
                atomicMax(&gkeys[1], kmx);
            }
        } else {
            v[jj] = (float)(1.0 / a);
        }
    }
}

// ---------------- select: candidate rerank (A) or full-row histogram (B) ----------------
constexpr int TK_T = 256;
constexpr int NB = 1024;
constexpr int MAXC = 128;

__device__ __forceinline__ int qbin(float x, float lo, float scale) {
    int q = (int)((x - lo) * scale);
    return max(0, min(NB - 1, q));
}

__global__ __launch_bounds__(TK_T, 4)
void topk_select(const float* __restrict__ D, const double* __restrict__ lvd,
                 const float* __restrict__ lvf, const unsigned* __restrict__ gkeys,
                 const unsigned short* __restrict__ candIdx,
                 const float* __restrict__ candD,
                 const unsigned* __restrict__ candCnt, int useCand,
                 float* __restrict__ out)
{
    __shared__ float slds[NN];          // 32 KB (B: scores; A: aliased cand arrays)
    __shared__ unsigned hist[NB];
    __shared__ int cIdxB[MAXC];
    __shared__ double cScoreB[MAXC];
    __shared__ unsigned char cSelB[MAXC];
    __shared__ int sSelBin, sAbove, sThrCnt, sCand;
    __shared__ float sLo, sScale;

    const int t = threadIdx.x;
    const int wave = t >> 6, lane = t & 63;
    const long row = blockIdx.x;
    float* __restrict__ orow = out + row * (long)NN;

    const int cnt = useCand ? (int)candCnt[row] : -1;
    if (cnt >= 48 && cnt <= CAP) {
        // ---- path A: exact fp64 rerank of candidates; no D re-read ----
        double* aS = (double*)slds;                       // CAP*8 = 4608 B
        unsigned short* aI = (unsigned short*)(slds + 1536);  // CAP*2 B
        const long rowOff = row * (long)CAP;
        for (int i = t; i < cnt; i += TK_T) {
            int ci = candIdx[rowOff + i];
            aI[i] = (unsigned short)ci;
            aS[i] = lvd[ci] - (double)candD[rowOff + i];
        }
        __syncthreads();
        for (int i = t; i < cnt; i += TK_T) {
            double si = aS[i];
            int ii = aI[i];
            int rank = 0;
            for (int k = 0; k < cnt; ++k) {
                double sk = aS[k];
                rank += (sk > si) || (sk == si && (int)aI[k] < ii);
            }
            if (rank < TOPK) orow[ii] = 1.0f;
        }
        return;
    }

    // ---- path B: full-row fused-histogram select (round-10 machinery) ----
    const float* __restrict__ Drow = D + row * (long)NN;
    const float4* __restrict__ Drow4 = (const float4*)Drow;
    const float4* __restrict__ lvf4 = (const float4*)lvf;
    float4* __restrict__ slds4 = (float4*)slds;

#pragma unroll
    for (int h = 0; h < NB / TK_T; ++h) hist[h * TK_T + t] = 0u;
    if (t == 0) {
        float lo = fkeyinv(gkeys[0]) - 6.5f;
        float hi = fkeyinv(gkeys[1]) + 6.5f;
        sLo = lo;
        sScale = ((float)NB / (hi - lo)) * 0.999999f;
        sCand = 0;
    }
    __syncthreads();
    const float lo0 = sLo, scale0 = sScale;

#pragma unroll
    for (int c = 0; c < 8; ++c) {
        int i4 = c * TK_T + t;
        float4 d = Drow4[i4];
        float4 l = lvf4[i4];
        float4 sc;
        sc.x = l.x - d.x; sc.y = l.y - d.y; sc.z = l.z - d.z; sc.w = l.w - d.w;
        slds4[i4] = sc;
        atomicAdd(&hist[qbin(sc.x, lo0, scale0)], 1u);
        atomicAdd(&hist[qbin(sc.y, lo0, scale0)], 1u);
        atomicAdd(&hist[qbin(sc.z, lo0, scale0)], 1u);
        atomicAdd(&hist[qbin(sc.w, lo0, scale0)], 1u);
    }
    __syncthreads();

    unsigned memberMask = 0xFFFFFFFFu;
    unsigned selMask = 0u;
    float lo = lo0, scale = scale0;
    int rem = TOPK;

    for (int lvl = 0; ; ++lvl) {
        if (wave == 0) {
            const int b0 = lane * 16;
            unsigned csum = 0;
#pragma unroll
            for (int b = 0; b < 16; ++b) csum += hist[b0 + ((b + lane) & 15)];
            unsigned suf = csum;
#pragma unroll
            for (int o = 1; o <= 32; o <<= 1) {
                unsigned other = __shfl_down(suf, o, 64);
                if (lane + o < 64) suf += other;
            }
            unsigned long long ball = __ballot(suf >= (unsigned)rem);
            int L = 63 - __clzll(ball);
            if (lane == L) {
                unsigned run = suf - csum;
                int bin = b0 + 15;
                for (; bin > b0; --bin) {
                    run += hist[bin];
                    if (run >= (unsigned)rem) break;
                }
                if (run < (unsigned)rem) run += hist[bin];
                sSelBin = bin;
                sAbove = (int)(run - hist[bin]);
                sThrCnt = (int)hist[bin];
            }
        }
        __syncthreads();
        const int selBin = sSelBin;
        const int thrCnt = sThrCnt;
        rem -= sAbove;

        unsigned newMember = 0u;
#pragma unroll
        for (int e = 0; e < 32; ++e)
            if ((memberMask >> e) & 1u) {
                int q = qbin(slds[e * TK_T + t], lo, scale);
                if (q > selBin) selMask |= 1u << e;
                else if (q == selBin) newMember |= 1u << e;
            }
        memberMask = newMember;

        bool refine = (thrCnt > MAXC) && (lvl < 3) && (scale < 1.0e30f);
        if (!refine) break;
        float w = 1.0f / scale;
        lo = lo + (float)selBin * w;
        scale = scale * (float)NB;
        __syncthreads();
#pragma unroll
        for (int h = 0; h < NB / TK_T; ++h) hist[h * TK_T + t] = 0u;
        __syncthreads();
#pragma unroll
        for (int e = 0; e < 32; ++e)
            if ((memberMask >> e) & 1u)
                atomicAdd(&hist[qbin(slds[e * TK_T + t], lo, scale)], 1u);
        __syncthreads();
    }

#pragma unroll
    for (int e = 0; e < 32; ++e)
        if ((memberMask >> e) & 1u) {
            int pos = atomicAdd(&sCand, 1);
            if (pos < MAXC) cIdxB[pos] = e * TK_T + t;
        }
    __syncthreads();
    const int bcnt = min(sCand, MAXC);

    for (int i = t; i < bcnt; i += TK_T) {
        int ci = cIdxB[i];
        cScoreB[i] = lvd[ci] - (double)Drow[ci];
    }
    __syncthreads();
    for (int i = t; i < bcnt; i += TK_T) {
        int ci = cIdxB[i];
        double si = cScoreB[i];
        int rank = 0;
        for (int k = 0; k < bcnt; ++k) {
            double sk = cScoreB[k];
            int ck = cIdxB[k];
            rank += (sk > si) || (sk == si && ck < ci);
        }
        cSelB[i] = (rank < rem) ? 1 : 0;
    }
    __syncthreads();

#pragma unroll
    for (int e = 0; e < 32; ++e)
        if ((selMask >> e) & 1u) orow[e * TK_T + t] = 1.0f;
    for (int i = t; i < bcnt; i += TK_T)
        if (cSelB[i]) orow[cIdxB[i]] = 1.0f;
}

// ---------------- launch ----------------
extern "C" void kernel_launch(void* const* d_in, const int* in_sizes, int n_in,
                              void* d_out, int out_size, void* d_ws, size_t ws_size,
                              hipStream_t stream)
{
    const float* D = (const float*)d_in[0];
    float* out = (float*)d_out;

    char* ws = (char*)d_ws;
    float*    v     = (float*)ws;                               // 32 KB
    float*    lvf   = (float*)(ws + 64 * 1024);                 // 32 KB
    double*   lvd   = (double*)(ws + 128 * 1024);               // 64 KB
    unsigned* gkeys = (unsigned*)(ws + 192 * 1024);             // 8 B
    unsigned* candCnt = (unsigned*)(ws + 200 * 1024);           // 32 KB
    float*    partials = (float*)(ws + 256 * 1024);             // nwg*32 KB
    const size_t fixed = 256 * 1024;

    int nwg = 512;
    while (nwg > 16 && fixed + (size_t)nwg * NN * 4 > ws_size) nwg >>= 1;
    const int rowsPerWg = NN / nwg;

    const size_t partEnd = fixed + (size_t)nwg * NN * 4;
    unsigned short* candIdx = (unsigned short*)(ws + partEnd);
    float* candD = (float*)(ws + partEnd + (size_t)CAP * NN * 2);
    const size_t needCand = partEnd + (size_t)CAP * NN * 2 + (size_t)CAP * NN * 4;
    const int useCand = (nwg == 512) && (ws_size >= needCand);

    fill_zero<<<NN, 256, 0, stream>>>(out, gkeys);
    for (int it = 0; it < NITER_RUN; ++it) {
        const int lastIt = (it == NITER_RUN - 1);
        if (lastIt && useCand)
            sinkhorn_cand<<<nwg, IT_T, 0, stream>>>(
                (const float4*)D, (const float4*)v, (float4*)partials,
                candIdx, candD, candCnt, rowsPerWg);
        else
            sinkhorn_iter<<<nwg, IT_T, 0, stream>>>(
                (const float4*)D, (const float4*)v, (float4*)partials,
                rowsPerWg, it == 0);
        col_reduce<<<NN / 32, 256, 0, stream>>>(partials, nwg, v, lvd, lvf, gkeys,
                                                lastIt);
    }
    topk_select<<<NN, TK_T, 0, stream>>>(D, lvd, lvf, gkeys,
                                         candIdx, candD, candCnt, useCand, out);
}

// Round 12
// 458.108 us; speedup vs baseline: 1.8470x; 1.8470x over previous
//
#include <hip/hip_runtime.h>
#include <math.h>

// SinkhornSort: P = diag(u) exp(-D) diag(v); u=1/(Kv), v=1/(K^T u), v0=1.
// Row ranking depends only on s_ij = log(v_j) - D_ij -> never materialize P.
// 3 iterations suffice (truncation ~1e-8 << shared fp32 noise ~1e-7; measured
// absmax==0 at 6, 4, 3 iters). Output = zero-fill + scatter 32 ones/row.
//
// Last sweep emits per-row candidates {col, D_ij} where exp(-D)*v >= rowmax*e^-1.85
// (cheap divergent atomic; ~3.5% emit rate). If 48 <= cnt <= CAP the top-32 is
// provably inside (cnt>=48 -> rank-48 above threshold) and select ranks ONLY the
// candidates via histogram-select (O(cnt)); else full-row fallback (round-10 path).

#define NN 8192
#define NITER_RUN 3
#define TOPK 32
#define CAP 576
#define THRF 0.15723717f   // e^-1.85
#define TCAPA 192

typedef float nf4 __attribute__((ext_vector_type(4)));

__device__ __forceinline__ unsigned fkey(float f) {
    unsigned b = __float_as_uint(f);
    return (b & 0x80000000u) ? ~b : (b | 0x80000000u);
}
__device__ __forceinline__ float fkeyinv(unsigned k) {
    unsigned b = (k & 0x80000000u) ? (k & 0x7FFFFFFFu) : ~k;
    return __uint_as_float(b);
}

// ---------------- zero-fill output (non-temporal; also inits gkeys) ----------------
__global__ __launch_bounds__(256)
void fill_zero(float* __restrict__ out, unsigned* __restrict__ gkeys)
{
    if (blockIdx.x == 0 && threadIdx.x == 0) { gkeys[0] = 0xFFFFFFFFu; gkeys[1] = 0u; }
    nf4* __restrict__ o4 = (nf4*)out;
    const long base = (long)blockIdx.x * 2048 + threadIdx.x;
    nf4 z = { 0.f, 0.f, 0.f, 0.f };
#pragma unroll
    for (int c = 0; c < 8; ++c)
        __builtin_nontemporal_store(z, &o4[base + (long)c * 256]);
}

// ---------------- lean Sinkhorn iteration (non-last) ----------------
constexpr int IT_T = 512;

__global__ __launch_bounds__(IT_T, 4)
void sinkhorn_iter(const float4* __restrict__ D4, const float4* __restrict__ v4,
                   float4* __restrict__ part4, int rowsPerWg, int first)
{
    const int t = threadIdx.x;
    const int wave = t >> 6, lane = t & 63;
    __shared__ float wred[2][IT_T / 64];

    float4 vreg[4], cacc[4];
#pragma unroll
    for (int c = 0; c < 4; ++c) {
        vreg[c] = first ? make_float4(1.f, 1.f, 1.f, 1.f) : v4[c * IT_T + t];
        cacc[c] = make_float4(0.f, 0.f, 0.f, 0.f);
    }

    const long rowBase = (long)blockIdx.x * rowsPerWg;
    for (int r = 0; r < rowsPerWg; r += 2) {
        float4 ev[2][4];
#pragma unroll
        for (int rr = 0; rr < 2; ++rr) {
            const float4* __restrict__ Dr = D4 + (rowBase + r + rr) * (long)(NN / 4);
            float rs = 0.f;
#pragma unroll
            for (int c = 0; c < 4; ++c) {
                float4 d = Dr[c * IT_T + t];
                float4 e;
                e.x = __expf(-d.x); e.y = __expf(-d.y);
                e.z = __expf(-d.z); e.w = __expf(-d.w);
                ev[rr][c] = e;
                rs += e.x * vreg[c].x + e.y * vreg[c].y
                    + e.z * vreg[c].z + e.w * vreg[c].w;
            }
#pragma unroll
            for (int o = 32; o >= 1; o >>= 1) rs += __shfl_down(rs, o, 64);
            if (lane == 0) wred[rr][wave] = rs;
        }
        __syncthreads();
        float tot0 = 0.f, tot1 = 0.f;
#pragma unroll
        for (int w = 0; w < IT_T / 64; ++w) { tot0 += wred[0][w]; tot1 += wred[1][w]; }
        const float u0 = 1.0f / tot0, u1 = 1.0f / tot1;
#pragma unroll
        for (int c = 0; c < 4; ++c) {
            cacc[c].x += ev[0][c].x * u0 + ev[1][c].x * u1;
            cacc[c].y += ev[0][c].y * u0 + ev[1][c].y * u1;
            cacc[c].z += ev[0][c].z * u0 + ev[1][c].z * u1;
            cacc[c].w += ev[0][c].w * u0 + ev[1][c].w * u1;
        }
        __syncthreads();
    }

    float4* __restrict__ pr = part4 + (long)blockIdx.x * (NN / 4);
#pragma unroll
    for (int c = 0; c < 4; ++c) pr[c * IT_T + t] = cacc[c];
}

// ---------------- last Sinkhorn iteration + cheap candidate emission ----------------
__global__ __launch_bounds__(IT_T, 4)
void sinkhorn_cand(const float4* __restrict__ D4, const float4* __restrict__ v4,
                   float4* __restrict__ part4,
                   unsigned short* __restrict__ candIdx,
                   float* __restrict__ candD,
                   unsigned* __restrict__ candCnt, int rowsPerWg)
{
    const int t = threadIdx.x;
    const int wave = t >> 6, lane = t & 63;
    __shared__ float wred[2][IT_T / 64];
    __shared__ float wmax[2][IT_T / 64];
    __shared__ unsigned rowCnt[2];

    float4 vreg[4], cacc[4];
#pragma unroll
    for (int c = 0; c < 4; ++c) {
        vreg[c] = v4[c * IT_T + t];
        cacc[c] = make_float4(0.f, 0.f, 0.f, 0.f);
    }
    if (t < 2) rowCnt[t] = 0;
    __syncthreads();

    const long rowBase = (long)blockIdx.x * rowsPerWg;
    for (int r = 0; r < rowsPerWg; r += 2) {
        float4 dv[2][4];
        // pass 1: row-sum and row-max of t = exp(-D)*v; keep D in registers
#pragma unroll
        for (int rr = 0; rr < 2; ++rr) {
            const float4* __restrict__ Dr = D4 + (rowBase + r + rr) * (long)(NN / 4);
            float rs = 0.f, tm = 0.f;
#pragma unroll
            for (int c = 0; c < 4; ++c) {
                float4 d = Dr[c * IT_T + t];
                dv[rr][c] = d;
                float px = __expf(-d.x) * vreg[c].x, py = __expf(-d.y) * vreg[c].y;
                float pz = __expf(-d.z) * vreg[c].z, pw = __expf(-d.w) * vreg[c].w;
                rs += px + py + pz + pw;
                tm = fmaxf(tm, fmaxf(fmaxf(px, py), fmaxf(pz, pw)));
            }
#pragma unroll
            for (int o = 32; o >= 1; o >>= 1) {
                rs += __shfl_down(rs, o, 64);
                tm = fmaxf(tm, __shfl_down(tm, o, 64));
            }
            if (lane == 0) { wred[rr][wave] = rs; wmax[rr][wave] = tm; }
        }
        __syncthreads();
        float tot0 = 0.f, tot1 = 0.f, m0 = 0.f, m1 = 0.f;
#pragma unroll
        for (int w = 0; w < IT_T / 64; ++w) {
            tot0 += wred[0][w]; tot1 += wred[1][w];
            m0 = fmaxf(m0, wmax[0][w]); m1 = fmaxf(m1, wmax[1][w]);
        }
        const float u0 = 1.0f / tot0, u1 = 1.0f / tot1;
        const float tau0 = m0 * THRF, tau1 = m1 * THRF;

        // pass 2: column accumulate + rare divergent emission
#pragma unroll
        for (int rr = 0; rr < 2; ++rr) {
            const float u = rr ? u1 : u0;
            const float tau = rr ? tau1 : tau0;
            const long rowOff = (rowBase + r + rr) * (long)CAP;

#define PROC(DD, VV, CCREF, COL)                                              \
            {                                                                 \
                float d_ = (DD);                                              \
                float e_ = __expf(-d_);                                       \
                CCREF += e_ * u;                                              \
                if (e_ * (VV) >= tau) {                                       \
                    unsigned pos_ = atomicAdd(&rowCnt[rr], 1u);               \
                    if (pos_ < CAP) {                                         \
                        candIdx[rowOff + pos_] = (unsigned short)(COL);       \
                        candD[rowOff + pos_] = d_;                            \
                    }                                                         \
                }                                                             \
            }

#pragma unroll
            for (int c = 0; c < 4; ++c) {
                const int colBase = (c * IT_T + t) * 4;
                PROC(dv[rr][c].x, vreg[c].x, cacc[c].x, colBase + 0)
                PROC(dv[rr][c].y, vreg[c].y, cacc[c].y, colBase + 1)
                PROC(dv[rr][c].z, vreg[c].z, cacc[c].z, colBase + 2)
                PROC(dv[rr][c].w, vreg[c].w, cacc[c].w, colBase + 3)
            }
#undef PROC
        }
        __syncthreads();
        if (t < 2) {
            candCnt[rowBase + r + t] = rowCnt[t];
            rowCnt[t] = 0;   // ordered before next batch's emits by its mid-barrier
        }
    }

    float4* __restrict__ pr = part4 + (long)blockIdx.x * (NN / 4);
#pragma unroll
    for (int c = 0; c < 4; ++c) pr[c * IT_T + t] = cacc[c];
}

// ---------------- deterministic fused column reduction ----------------
__global__ __launch_bounds__(256)
void col_reduce(const float* __restrict__ partials, int nStrips,
                float* __restrict__ v, double* __restrict__ lvd,
                float* __restrict__ lvf, unsigned* __restrict__ gkeys, int last)
{
    __shared__ double sums[8][33];
    const int jl = threadIdx.x & 31, sg = threadIdx.x >> 5;
    const int j = blockIdx.x * 32 + jl;
    double acc = 0.0;
#pragma unroll 4
    for (int s = sg; s < nStrips; s += 8)
        acc += (double)partials[(long)s * NN + j];
    sums[sg][jl] = acc;
    __syncthreads();
    if (threadIdx.x < 32) {
        double a = 0.0;
#pragma unroll
        for (int g = 0; g < 8; ++g) a += sums[g][threadIdx.x];
        int jj = blockIdx.x * 32 + threadIdx.x;
        if (last) {
            double lv = -log(a);
            lvd[jj] = lv;
            float lf = (float)lv;
            lvf[jj] = lf;
            unsigned k = fkey(lf), kmn = k, kmx = k;
#pragma unroll
            for (int o = 16; o >= 1; o >>= 1) {
                kmn = min(kmn, (unsigned)__shfl_down((int)kmn, o, 64));
                kmx = max(kmx, (unsigned)__shfl_down((int)kmx, o, 64));
            }
            if (threadIdx.x == 0) {
                atomicMin(&gkeys[0], kmn);
                atomicMax(&gkeys[1], kmx);
            }
        } else {
            v[jj] = (float)(1.0 / a);
        }
    }
}

// ---------------- select: candidate histogram-select (A) or full-row (B) ----------------
constexpr int TK_T = 256;
constexpr int NB = 1024;
constexpr int MAXC = 128;

__device__ __forceinline__ int qbin(float x, float lo, float scale) {
    int q = (int)((x - lo) * scale);
    return max(0, min(NB - 1, q));
}

__global__ __launch_bounds__(TK_T, 4)
void topk_select(const float* __restrict__ D, const double* __restrict__ lvd,
                 const float* __restrict__ lvf, const unsigned* __restrict__ gkeys,
                 const unsigned short* __restrict__ candIdx,
                 const float* __restrict__ candD,
                 const unsigned* __restrict__ candCnt, int useCand,
                 float* __restrict__ out)
{
    __shared__ float slds[NN];          // 32 KB; path A aliases sub-arrays below
    __shared__ unsigned hist[NB];
    __shared__ float rbuf[8];
    __shared__ int cIdxB[MAXC];
    __shared__ double cScoreB[MAXC];
    __shared__ unsigned char cSelB[MAXC];
    __shared__ int sSelBin, sAbove, sThrCnt, sCand;
    __shared__ float sLo, sScale;

    const int t = threadIdx.x;
    const int wave = t >> 6, lane = t & 63;
    const long row = blockIdx.x;
    float* __restrict__ orow = out + row * (long)NN;

    const int cnt = useCand ? (int)candCnt[row] : -1;
    if (cnt >= 48 && cnt <= CAP) {
        // ---- path A: histogram-select over candidates only; no D re-read ----
        float* aS = slds;                                    // [0,576) f32 keys
        float* aD = slds + 576;                              // f32 D values
        unsigned short* aI = (unsigned short*)(slds + 1152); // u16 cols
        int* tIdx = (int*)(slds + 1440);                     // threshold-bin items
        const long rowOff = row * (long)CAP;

        float mn = 3.0e38f, mx = -3.0e38f;
        for (int i = t; i < cnt; i += TK_T) {
            int ci = candIdx[rowOff + i];
            float d = candD[rowOff + i];
            float s = lvf[ci] - d;
            aS[i] = s; aD[i] = d; aI[i] = (unsigned short)ci;
            mn = fminf(mn, s); mx = fmaxf(mx, s);
        }
#pragma unroll
        for (int o = 32; o >= 1; o >>= 1) {
            mn = fminf(mn, __shfl_down(mn, o, 64));
            mx = fmaxf(mx, __shfl_down(mx, o, 64));
        }
        if (lane == 0) { rbuf[wave] = mn; rbuf[4 + wave] = mx; }
#pragma unroll
        for (int h = 0; h < NB / TK_T; ++h) hist[h * TK_T + t] = 0u;
        if (t == 0) sCand = 0;
        __syncthreads();
        if (t == 0) {
            float m0 = fminf(fminf(rbuf[0], rbuf[1]), fminf(rbuf[2], rbuf[3]));
            float m1 = fmaxf(fmaxf(rbuf[4], rbuf[5]), fmaxf(rbuf[6], rbuf[7]));
            float range = m1 - m0;
            sLo = m0;
            sScale = (range > 0.f) ? ((float)NB / range) * 0.999999f : 0.f;
        }
        __syncthreads();
        const float lo = sLo, scale = sScale;
        for (int i = t; i < cnt; i += TK_T)
            atomicAdd(&hist[qbin(aS[i], lo, scale)], 1u);
        __syncthreads();

        if (wave == 0) {
            const int b0 = lane * 16;
            unsigned csum = 0;
#pragma unroll
            for (int b = 0; b < 16; ++b) csum += hist[b0 + ((b + lane) & 15)];
            unsigned suf = csum;
#pragma unroll
            for (int o = 1; o <= 32; o <<= 1) {
                unsigned other = __shfl_down(suf, o, 64);
                if (lane + o < 64) suf += other;
            }
            unsigned long long ball = __ballot(suf >= (unsigned)TOPK);
            int L = 63 - __clzll(ball);
            if (lane == L) {
                unsigned run = suf - csum;
                int bin = b0 + 15;
                for (; bin > b0; --bin) {
                    run += hist[bin];
                    if (run >= (unsigned)TOPK) break;
                }
                if (run < (unsigned)TOPK) run += hist[bin];
                sSelBin = bin;
                sAbove = (int)(run - hist[bin]);
            }
        }
        __syncthreads();
        const int selBin = sSelBin;
        const int rem = TOPK - sAbove;    // >=1 slots inside threshold bin

        for (int i = t; i < cnt; i += TK_T) {
            int q = qbin(aS[i], lo, scale);
            if (q > selBin) orow[aI[i]] = 1.0f;
            else if (q == selBin) {
                int pos = atomicAdd(&sCand, 1);
                if (pos < TCAPA) tIdx[pos] = i;
            }
        }
        __syncthreads();
        const int tcnt = sCand;
        if (tcnt <= TCAPA) {
            // exact fp64 rank among threshold-bin items (jax tie rule)
            for (int i = t; i < tcnt; i += TK_T) {
                int ii = tIdx[i];
                int ci = aI[ii];
                double si = lvd[ci] - (double)aD[ii];
                int rank = 0;
                for (int k = 0; k < tcnt; ++k) {
                    int kk = tIdx[k];
                    int ck = aI[kk];
                    double sk = lvd[ck] - (double)aD[kk];
                    rank += (sk > si) || (sk == si && ck < ci);
                }
                if (rank < rem) orow[ci] = 1.0f;
            }
        } else {
            // degenerate (>TCAPA keys in one bin): full fp64 rank over candidates
            double* aSd = (double*)(slds + 2048);
            for (int i = t; i < cnt; i += TK_T)
                aSd[i] = lvd[aI[i]] - (double)aD[i];
            __syncthreads();
            for (int i = t; i < cnt; i += TK_T) {
                double si = aSd[i];
                int ci = aI[i];
                int rank = 0;
                for (int k = 0; k < cnt; ++k) {
                    double sk = aSd[k];
                    rank += (sk > si) || (sk == si && (int)aI[k] < ci);
                }
                if (rank < TOPK) { /* overwrite any bin-based writes: set below */ }
                orow[ci] = (rank < TOPK) ? 1.0f : orow[ci];
            }
        }
        return;
    }

    // ---- path B: full-row fused-histogram select (round-10 machinery) ----
    const float* __restrict__ Drow = D + row * (long)NN;
    const float4* __restrict__ Drow4 = (const float4*)Drow;
    const float4* __restrict__ lvf4 = (const float4*)lvf;
    float4* __restrict__ slds4 = (float4*)slds;

#pragma unroll
    for (int h = 0; h < NB / TK_T; ++h) hist[h * TK_T + t] = 0u;
    if (t == 0) {
        float lo = fkeyinv(gkeys[0]) - 6.5f;
        float hi = fkeyinv(gkeys[1]) + 6.5f;
        sLo = lo;
        sScale = ((float)NB / (hi - lo)) * 0.999999f;
        sCand = 0;
    }
    __syncthreads();
    const float lo0 = sLo, scale0 = sScale;

#pragma unroll
    for (int c = 0; c < 8; ++c) {
        int i4 = c * TK_T + t;
        float4 d = Drow4[i4];
        float4 l = lvf4[i4];
        float4 sc;
        sc.x = l.x - d.x; sc.y = l.y - d.y; sc.z = l.z - d.z; sc.w = l.w - d.w;
        slds4[i4] = sc;
        atomicAdd(&hist[qbin(sc.x, lo0, scale0)], 1u);
        atomicAdd(&hist[qbin(sc.y, lo0, scale0)], 1u);
        atomicAdd(&hist[qbin(sc.z, lo0, scale0)], 1u);
        atomicAdd(&hist[qbin(sc.w, lo0, scale0)], 1u);
    }
    __syncthreads();

    unsigned memberMask = 0xFFFFFFFFu;
    unsigned selMask = 0u;
    float lo = lo0, scale = scale0;
    int rem = TOPK;

    for (int lvl = 0; ; ++lvl) {
        if (wave == 0) {
            const int b0 = lane * 16;
            unsigned csum = 0;
#pragma unroll
            for (int b = 0; b < 16; ++b) csum += hist[b0 + ((b + lane) & 15)];
            unsigned suf = csum;
#pragma unroll
            for (int o = 1; o <= 32; o <<= 1) {
                unsigned other = __shfl_down(suf, o, 64);
                if (lane + o < 64) suf += other;
            }
            unsigned long long ball = __ballot(suf >= (unsigned)rem);
            int L = 63 - __clzll(ball);
            if (lane == L) {
                unsigned run = suf - csum;
                int bin = b0 + 15;
                for (; bin > b0; --bin) {
                    run += hist[bin];
                    if (run >= (unsigned)rem) break;
                }
                if (run < (unsigned)rem) run += hist[bin];
                sSelBin = bin;
                sAbove = (int)(run - hist[bin]);
                sThrCnt = (int)hist[bin];
            }
        }
        __syncthreads();
        const int selBin = sSelBin;
        const int thrCnt = sThrCnt;
        rem -= sAbove;

        unsigned newMember = 0u;
#pragma unroll
        for (int e = 0; e < 32; ++e)
            if ((memberMask >> e) & 1u) {
                int q = qbin(slds[e * TK_T + t], lo, scale);
                if (q > selBin) selMask |= 1u << e;
                else if (q == selBin) newMember |= 1u << e;
            }
        memberMask = newMember;

        bool refine = (thrCnt > MAXC) && (lvl < 3) && (scale < 1.0e30f);
        if (!refine) break;
        float w = 1.0f / scale;
        lo = lo + (float)selBin * w;
        scale = scale * (float)NB;
        __syncthreads();
#pragma unroll
        for (int h = 0; h < NB / TK_T; ++h) hist[h * TK_T + t] = 0u;
        __syncthreads();
#pragma unroll
        for (int e = 0; e < 32; ++e)
            if ((memberMask >> e) & 1u)
                atomicAdd(&hist[qbin(slds[e * TK_T + t], lo, scale)], 1u);
        __syncthreads();
    }

#pragma unroll
    for (int e = 0; e < 32; ++e)
        if ((memberMask >> e) & 1u) {
            int pos = atomicAdd(&sCand, 1);
            if (pos < MAXC) cIdxB[pos] = e * TK_T + t;
        }
    __syncthreads();
    const int bcnt = min(sCand, MAXC);

    for (int i = t; i < bcnt; i += TK_T) {
        int ci = cIdxB[i];
        cScoreB[i] = lvd[ci] - (double)Drow[ci];
    }
    __syncthreads();
    for (int i = t; i < bcnt; i += TK_T) {
        int ci = cIdxB[i];
        double si = cScoreB[i];
        int rank = 0;
        for (int k = 0; k < bcnt; ++k) {
            double sk = cScoreB[k];
            int ck = cIdxB[k];
            rank += (sk > si) || (sk == si && ck < ci);
        }
        cSelB[i] = (rank < rem) ? 1 : 0;
    }
    __syncthreads();

#pragma unroll
    for (int e = 0; e < 32; ++e)
        if ((selMask >> e) & 1u) orow[e * TK_T + t] = 1.0f;
    for (int i = t; i < bcnt; i += TK_T)
        if (cSelB[i]) orow[cIdxB[i]] = 1.0f;
}

// ---------------- launch ----------------
extern "C" void kernel_launch(void* const* d_in, const int* in_sizes, int n_in,
                              void* d_out, int out_size, void* d_ws, size_t ws_size,
                              hipStream_t stream)
{
    const float* D = (const float*)d_in[0];
    float* out = (float*)d_out;

    char* ws = (char*)d_ws;
    float*    v     = (float*)ws;                               // 32 KB
    float*    lvf   = (float*)(ws + 64 * 1024);                 // 32 KB
    double*   lvd   = (double*)(ws + 128 * 1024);               // 64 KB
    unsigned* gkeys = (unsigned*)(ws + 192 * 1024);             // 8 B
    unsigned* candCnt = (unsigned*)(ws + 200 * 1024);           // 32 KB
    float*    partials = (float*)(ws + 256 * 1024);             // nwg*32 KB
    const size_t fixed = 256 * 1024;

    int nwg = 512;
    while (nwg > 16 && fixed + (size_t)nwg * NN * 4 > ws_size) nwg >>= 1;
    const int rowsPerWg = NN / nwg;

    const size_t partEnd = fixed + (size_t)nwg * NN * 4;
    unsigned short* candIdx = (unsigned short*)(ws + partEnd);
    float* candD = (float*)(ws + partEnd + (size_t)CAP * NN * 2);
    const size_t needCand = partEnd + (size_t)CAP * NN * 2 + (size_t)CAP * NN * 4;
    const int useCand = (nwg == 512) && (ws_size >= needCand);

    fill_zero<<<NN, 256, 0, stream>>>(out, gkeys);
    for (int it = 0; it < NITER_RUN; ++it) {
        const int lastIt = (it == NITER_RUN - 1);
        if (lastIt && useCand)
            sinkhorn_cand<<<nwg, IT_T, 0, stream>>>(
                (const float4*)D, (const float4*)v, (float4*)partials,
                candIdx, candD, candCnt, rowsPerWg);
        else
            sinkhorn_iter<<<nwg, IT_T, 0, stream>>>(
                (const float4*)D, (const float4*)v, (float4*)partials,
                rowsPerWg, it == 0);
        col_reduce<<<NN / 32, 256, 0, stream>>>(partials, nwg, v, lvd, lvf, gkeys,
                                                lastIt);
    }
    topk_select<<<NN, TK_T, 0, stream>>>(D, lvd, lvf, gkeys,
                                         candIdx, candD, candCnt, useCand, out);
}

// Round 13
// 274.685 us; speedup vs baseline: 3.0804x; 1.6678x over previous
//
#include <hip/hip_runtime.h>
#include <math.h>

// SinkhornSort: P = diag(u) exp(-D) diag(v); u=1/(Kv), v=1/(K^T u), v0=1.
// Row ranking depends only on s_ij = log(v_j) - D_ij -> never materialize P.
// 3 iterations suffice (truncation ~1e-8 << shared fp32 noise ~1e-7; measured
// absmax==0 at 6, 4, 3 iters). Output = zero-fill + scatter 32 ones/row.
//
// Last sweep emits per-row candidates {col, D_ij} where t = exp(-D)*v >=
// (rowsum(t)/N)*e^1.2  (predicate from the already-computed rs reduce; ~4.5%
// emit rate, cnt~365/row; top-32 inside with e^0.9 margin). Select ranks only
// the candidates (histogram-select, global bin range); full-row fallback if
// cnt<48 or cnt>CAP.

#define NN 8192
#define NITER_RUN 3
#define TOPK 32
#define CAP 576
#define TKFAC 3.3201169f   // e^1.2
#define TCAPA 192

typedef float nf4 __attribute__((ext_vector_type(4)));

__device__ __forceinline__ unsigned fkey(float f) {
    unsigned b = __float_as_uint(f);
    return (b & 0x80000000u) ? ~b : (b | 0x80000000u);
}
__device__ __forceinline__ float fkeyinv(unsigned k) {
    unsigned b = (k & 0x80000000u) ? (k & 0x7FFFFFFFu) : ~k;
    return __uint_as_float(b);
}

// ---------------- zero-fill output (non-temporal; also inits gkeys) ----------------
__global__ __launch_bounds__(256)
void fill_zero(float* __restrict__ out, unsigned* __restrict__ gkeys)
{
    if (blockIdx.x == 0 && threadIdx.x == 0) { gkeys[0] = 0xFFFFFFFFu; gkeys[1] = 0u; }
    nf4* __restrict__ o4 = (nf4*)out;
    const long base = (long)blockIdx.x * 2048 + threadIdx.x;
    nf4 z = { 0.f, 0.f, 0.f, 0.f };
#pragma unroll
    for (int c = 0; c < 8; ++c)
        __builtin_nontemporal_store(z, &o4[base + (long)c * 256]);
}

// ---------------- lean Sinkhorn iteration (non-last) ----------------
constexpr int IT_T = 512;

__global__ __launch_bounds__(IT_T, 4)
void sinkhorn_iter(const float4* __restrict__ D4, const float4* __restrict__ v4,
                   float4* __restrict__ part4, int rowsPerWg, int first)
{
    const int t = threadIdx.x;
    const int wave = t >> 6, lane = t & 63;
    __shared__ float wred[2][IT_T / 64];

    float4 vreg[4], cacc[4];
#pragma unroll
    for (int c = 0; c < 4; ++c) {
        vreg[c] = first ? make_float4(1.f, 1.f, 1.f, 1.f) : v4[c * IT_T + t];
        cacc[c] = make_float4(0.f, 0.f, 0.f, 0.f);
    }

    const long rowBase = (long)blockIdx.x * rowsPerWg;
    for (int r = 0; r < rowsPerWg; r += 2) {
        float4 ev[2][4];
#pragma unroll
        for (int rr = 0; rr < 2; ++rr) {
            const float4* __restrict__ Dr = D4 + (rowBase + r + rr) * (long)(NN / 4);
            float rs = 0.f;
#pragma unroll
            for (int c = 0; c < 4; ++c) {
                float4 d = Dr[c * IT_T + t];
                float4 e;
                e.x = __expf(-d.x); e.y = __expf(-d.y);
                e.z = __expf(-d.z); e.w = __expf(-d.w);
                ev[rr][c] = e;
                rs += e.x * vreg[c].x + e.y * vreg[c].y
                    + e.z * vreg[c].z + e.w * vreg[c].w;
            }
#pragma unroll
            for (int o = 32; o >= 1; o >>= 1) rs += __shfl_down(rs, o, 64);
            if (lane == 0) wred[rr][wave] = rs;
        }
        __syncthreads();
        float tot0 = 0.f, tot1 = 0.f;
#pragma unroll
        for (int w = 0; w < IT_T / 64; ++w) { tot0 += wred[0][w]; tot1 += wred[1][w]; }
        const float u0 = 1.0f / tot0, u1 = 1.0f / tot1;
#pragma unroll
        for (int c = 0; c < 4; ++c) {
            cacc[c].x += ev[0][c].x * u0 + ev[1][c].x * u1;
            cacc[c].y += ev[0][c].y * u0 + ev[1][c].y * u1;
            cacc[c].z += ev[0][c].z * u0 + ev[1][c].z * u1;
            cacc[c].w += ev[0][c].w * u0 + ev[1][c].w * u1;
        }
        __syncthreads();
    }

    float4* __restrict__ pr = part4 + (long)blockIdx.x * (NN / 4);
#pragma unroll
    for (int c = 0; c < 4; ++c) pr[c * IT_T + t] = cacc[c];
}

// ---------------- last Sinkhorn iteration + candidate emission ----------------
// One row per barrier (dv[4] only -> ~48 live regs, no spill). Threshold from rs.
__global__ __launch_bounds__(IT_T, 4)
void sinkhorn_cand(const float4* __restrict__ D4, const float4* __restrict__ v4,
                   float4* __restrict__ part4,
                   unsigned short* __restrict__ candIdx,
                   float* __restrict__ candD,
                   unsigned* __restrict__ candCnt, int rowsPerWg)
{
    const int t = threadIdx.x;
    const int wave = t >> 6, lane = t & 63;
    __shared__ float wred[2][IT_T / 64];
    __shared__ unsigned rowCnt[16];

    float4 vreg[4], cacc[4];
#pragma unroll
    for (int c = 0; c < 4; ++c) {
        vreg[c] = v4[c * IT_T + t];
        cacc[c] = make_float4(0.f, 0.f, 0.f, 0.f);
    }
    if (t < 16) rowCnt[t] = 0;
    __syncthreads();

    const long rowBase = (long)blockIdx.x * rowsPerWg;
    for (int r = 0; r < rowsPerWg; ++r) {
        const float4* __restrict__ Dr = D4 + (rowBase + r) * (long)(NN / 4);
        float4 dv[4];
        float rs = 0.f;
#pragma unroll
        for (int c = 0; c < 4; ++c) {
            float4 d = Dr[c * IT_T + t];
            dv[c] = d;
            rs += __expf(-d.x) * vreg[c].x + __expf(-d.y) * vreg[c].y
                + __expf(-d.z) * vreg[c].z + __expf(-d.w) * vreg[c].w;
        }
#pragma unroll
        for (int o = 32; o >= 1; o >>= 1) rs += __shfl_down(rs, o, 64);
        if (lane == 0) wred[r & 1][wave] = rs;
        __syncthreads();
        // wred[p] of row r first rewritten by pass1(r+2), which all threads reach
        // only after this row's pass2 completes (barrier r+1 intervenes). Safe.
        float tot = 0.f;
#pragma unroll
        for (int w = 0; w < IT_T / 64; ++w) tot += wred[r & 1][w];
        const float u = 1.0f / tot;
        const float tau = tot * (TKFAC / (float)NN);
        const long rowOff = (rowBase + r) * (long)CAP;

#define PROC(DD, VV, CCREF, COL)                                              \
        {                                                                     \
            float d_ = (DD);                                                  \
            float e_ = __expf(-d_);                                           \
            CCREF += e_ * u;                                                  \
            if (e_ * (VV) >= tau) {                                           \
                unsigned pos_ = atomicAdd(&rowCnt[r], 1u);                    \
                if (pos_ < CAP) {                                             \
                    candIdx[rowOff + pos_] = (unsigned short)(COL);           \
                    candD[rowOff + pos_] = d_;                                \
                }                                                             \
            }                                                                 \
        }

#pragma unroll
        for (int c = 0; c < 4; ++c) {
            const int colBase = (c * IT_T + t) * 4;
            PROC(dv[c].x, vreg[c].x, cacc[c].x, colBase + 0)
            PROC(dv[c].y, vreg[c].y, cacc[c].y, colBase + 1)
            PROC(dv[c].z, vreg[c].z, cacc[c].z, colBase + 2)
            PROC(dv[c].w, vreg[c].w, cacc[c].w, colBase + 3)
        }
#undef PROC
    }
    __syncthreads();
    if (t < 16) candCnt[rowBase + t] = rowCnt[t];

    float4* __restrict__ pr = part4 + (long)blockIdx.x * (NN / 4);
#pragma unroll
    for (int c = 0; c < 4; ++c) pr[c * IT_T + t] = cacc[c];
}

// ---------------- deterministic fused column reduction ----------------
__global__ __launch_bounds__(256)
void col_reduce(const float* __restrict__ partials, int nStrips,
                float* __restrict__ v, double* __restrict__ lvd,
                float* __restrict__ lvf, unsigned* __restrict__ gkeys, int last)
{
    __shared__ double sums[8][33];
    const int jl = threadIdx.x & 31, sg = threadIdx.x >> 5;
    const int j = blockIdx.x * 32 + jl;
    double acc = 0.0;
#pragma unroll 4
    for (int s = sg; s < nStrips; s += 8)
        acc += (double)partials[(long)s * NN + j];
    sums[sg][jl] = acc;
    __syncthreads();
    if (threadIdx.x < 32) {
        double a = 0.0;
#pragma unroll
        for (int g = 0; g < 8; ++g) a += sums[g][threadIdx.x];
        int jj = blockIdx.x * 32 + threadIdx.x;
        if (last) {
            double lv = -log(a);
            lvd[jj] = lv;
            float lf = (float)lv;
            lvf[jj] = lf;
            unsigned k = fkey(lf), kmn = k, kmx = k;
#pragma unroll
            for (int o = 16; o >= 1; o >>= 1) {
                kmn = min(kmn, (unsigned)__shfl_down((int)kmn, o, 64));
                kmx = max(kmx, (unsigned)__shfl_down((int)kmx, o, 64));
            }
            if (threadIdx.x == 0) {
                atomicMin(&gkeys[0], kmn);
                atomicMax(&gkeys[1], kmx);
            }
        } else {
            v[jj] = (float)(1.0 / a);
        }
    }
}

// ---------------- select: candidate histogram-select (A) or full-row (B) ----------------
constexpr int TK_T = 256;
constexpr int NB = 1024;
constexpr int MAXC = 128;

__device__ __forceinline__ int qbin(float x, float lo, float scale) {
    int q = (int)((x - lo) * scale);
    return max(0, min(NB - 1, q));
}

__global__ __launch_bounds__(TK_T, 4)
void topk_select(const float* __restrict__ D, const double* __restrict__ lvd,
                 const float* __restrict__ lvf, const unsigned* __restrict__ gkeys,
                 const unsigned short* __restrict__ candIdx,
                 const float* __restrict__ candD,
                 const unsigned* __restrict__ candCnt, int useCand,
                 float* __restrict__ out)
{
    __shared__ float slds[NN];          // 32 KB; path A aliases sub-arrays below
    __shared__ unsigned hist[NB];
    __shared__ int cIdxB[MAXC];
    __shared__ double cScoreB[MAXC];
    __shared__ unsigned char cSelB[MAXC];
    __shared__ int sSelBin, sAbove, sThrCnt, sCand;
    __shared__ float sLo, sScale;

    const int t = threadIdx.x;
    const int wave = t >> 6, lane = t & 63;
    const long row = blockIdx.x;
    float* __restrict__ orow = out + row * (long)NN;

    const int cnt = useCand ? (int)candCnt[row] : -1;
    if (cnt >= 48 && cnt <= CAP) {
        // ---- path A: histogram-select over candidates; global bin range ----
        float* aS = slds;                                    // f32 scores
        float* aD = slds + 576;                              // f32 D values
        unsigned short* aI = (unsigned short*)(slds + 1152); // u16 cols
        int* tIdx = (int*)(slds + 1440);                     // threshold-bin items
        const long rowOff = row * (long)CAP;

#pragma unroll
        for (int h = 0; h < NB / TK_T; ++h) hist[h * TK_T + t] = 0u;
        if (t == 0) {
            float lo = fkeyinv(gkeys[0]) - 6.5f;
            float hi = fkeyinv(gkeys[1]) + 6.5f;
            sLo = lo;
            sScale = ((float)NB / (hi - lo)) * 0.999999f;
            sCand = 0;
        }
        __syncthreads();
        const float lo = sLo, scale = sScale;

        for (int i = t; i < cnt; i += TK_T) {
            int ci = candIdx[rowOff + i];
            float d = candD[rowOff + i];
            float s = lvf[ci] - d;
            aS[i] = s; aD[i] = d; aI[i] = (unsigned short)ci;
            atomicAdd(&hist[qbin(s, lo, scale)], 1u);
        }
        __syncthreads();

        if (wave == 0) {
            const int b0 = lane * 16;
            unsigned csum = 0;
#pragma unroll
            for (int b = 0; b < 16; ++b) csum += hist[b0 + ((b + lane) & 15)];
            unsigned suf = csum;
#pragma unroll
            for (int o = 1; o <= 32; o <<= 1) {
                unsigned other = __shfl_down(suf, o, 64);
                if (lane + o < 64) suf += other;
            }
            unsigned long long ball = __ballot(suf >= (unsigned)TOPK);
            int L = 63 - __clzll(ball);
            if (lane == L) {
                unsigned run = suf - csum;
                int bin = b0 + 15;
                for (; bin > b0; --bin) {
                    run += hist[bin];
                    if (run >= (unsigned)TOPK) break;
                }
                if (run < (unsigned)TOPK) run += hist[bin];
                sSelBin = bin;
                sAbove = (int)(run - hist[bin]);
            }
        }
        __syncthreads();
        const int selBin = sSelBin;
        const int rem = TOPK - sAbove;    // >=1 slots inside threshold bin

        for (int i = t; i < cnt; i += TK_T) {
            int q = qbin(aS[i], lo, scale);
            if (q > selBin) orow[aI[i]] = 1.0f;
            else if (q == selBin) {
                int pos = atomicAdd(&sCand, 1);
                if (pos < TCAPA) tIdx[pos] = i;
            }
        }
        __syncthreads();
        const int tcnt = sCand;
        if (tcnt <= TCAPA) {
            for (int i = t; i < tcnt; i += TK_T) {
                int ii = tIdx[i];
                int ci = aI[ii];
                double si = lvd[ci] - (double)aD[ii];
                int rank = 0;
                for (int k = 0; k < tcnt; ++k) {
                    int kk = tIdx[k];
                    int ck = aI[kk];
                    double sk = lvd[ck] - (double)aD[kk];
                    rank += (sk > si) || (sk == si && ck < ci);
                }
                if (rank < rem) orow[ci] = 1.0f;
            }
        } else {
            // degenerate: full fp64 rank over all candidates
            double* aSd = (double*)(slds + 2048);
            for (int i = t; i < cnt; i += TK_T)
                aSd[i] = lvd[aI[i]] - (double)aD[i];
            __syncthreads();
            for (int i = t; i < cnt; i += TK_T) {
                double si = aSd[i];
                int ci = aI[i];
                int rank = 0;
                for (int k = 0; k < cnt; ++k) {
                    double sk = aSd[k];
                    rank += (sk > si) || (sk == si && (int)aI[k] < ci);
                }
                orow[ci] = (rank < TOPK) ? 1.0f : orow[ci];
            }
        }
        return;
    }

    // ---- path B: full-row fused-histogram select (round-10 machinery) ----
    const float* __restrict__ Drow = D + row * (long)NN;
    const float4* __restrict__ Drow4 = (const float4*)Drow;
    const float4* __restrict__ lvf4 = (const float4*)lvf;
    float4* __restrict__ slds4 = (float4*)slds;

#pragma unroll
    for (int h = 0; h < NB / TK_T; ++h) hist[h * TK_T + t] = 0u;
    if (t == 0) {
        float lo = fkeyinv(gkeys[0]) - 6.5f;
        float hi = fkeyinv(gkeys[1]) + 6.5f;
        sLo = lo;
        sScale = ((float)NB / (hi - lo)) * 0.999999f;
        sCand = 0;
    }
    __syncthreads();
    const float lo0 = sLo, scale0 = sScale;

#pragma unroll
    for (int c = 0; c < 8; ++c) {
        int i4 = c * TK_T + t;
        float4 d = Drow4[i4];
        float4 l = lvf4[i4];
        float4 sc;
        sc.x = l.x - d.x; sc.y = l.y - d.y; sc.z = l.z - d.z; sc.w = l.w - d.w;
        slds4[i4] = sc;
        atomicAdd(&hist[qbin(sc.x, lo0, scale0)], 1u);
        atomicAdd(&hist[qbin(sc.y, lo0, scale0)], 1u);
        atomicAdd(&hist[qbin(sc.z, lo0, scale0)], 1u);
        atomicAdd(&hist[qbin(sc.w, lo0, scale0)], 1u);
    }
    __syncthreads();

    unsigned memberMask = 0xFFFFFFFFu;
    unsigned selMask = 0u;
    float lo = lo0, scale = scale0;
    int rem = TOPK;

    for (int lvl = 0; ; ++lvl) {
        if (wave == 0) {
            const int b0 = lane * 16;
            unsigned csum = 0;
#pragma unroll
            for (int b = 0; b < 16; ++b) csum += hist[b0 + ((b + lane) & 15)];
            unsigned suf = csum;
#pragma unroll
            for (int o = 1; o <= 32; o <<= 1) {
                unsigned other = __shfl_down(suf, o, 64);
                if (lane + o < 64) suf += other;
            }
            unsigned long long ball = __ballot(suf >= (unsigned)rem);
            int L = 63 - __clzll(ball);
            if (lane == L) {
                unsigned run = suf - csum;
                int bin = b0 + 15;
                for (; bin > b0; --bin) {
                    run += hist[bin];
                    if (run >= (unsigned)rem) break;
                }
                if (run < (unsigned)rem) run += hist[bin];
                sSelBin = bin;
                sAbove = (int)(run - hist[bin]);
                sThrCnt = (int)hist[bin];
            }
        }
        __syncthreads();
        const int selBin = sSelBin;
        const int thrCnt = sThrCnt;
        rem -= sAbove;

        unsigned newMember = 0u;
#pragma unroll
        for (int e = 0; e < 32; ++e)
            if ((memberMask >> e) & 1u) {
                int q = qbin(slds[e * TK_T + t], lo, scale);
                if (q > selBin) selMask |= 1u << e;
                else if (q == selBin) newMember |= 1u << e;
            }
        memberMask = newMember;

        bool refine = (thrCnt > MAXC) && (lvl < 3) && (scale < 1.0e30f);
        if (!refine) break;
        float w = 1.0f / scale;
        lo = lo + (float)selBin * w;
        scale = scale * (float)NB;
        __syncthreads();
#pragma unroll
        for (int h = 0; h < NB / TK_T; ++h) hist[h * TK_T + t] = 0u;
        __syncthreads();
#pragma unroll
        for (int e = 0; e < 32; ++e)
            if ((memberMask >> e) & 1u)
                atomicAdd(&hist[qbin(slds[e * TK_T + t], lo, scale)], 1u);
        __syncthreads();
    }

#pragma unroll
    for (int e = 0; e < 32; ++e)
        if ((memberMask >> e) & 1u) {
            int pos = atomicAdd(&sCand, 1);
            if (pos < MAXC) cIdxB[pos] = e * TK_T + t;
        }
    __syncthreads();
    const int bcnt = min(sCand, MAXC);

    for (int i = t; i < bcnt; i += TK_T) {
        int ci = cIdxB[i];
        cScoreB[i] = lvd[ci] - (double)Drow[ci];
    }
    __syncthreads();
    for (int i = t; i < bcnt; i += TK_T) {
        int ci = cIdxB[i];
        double si = cScoreB[i];
        int rank = 0;
        for (int k = 0; k < bcnt; ++k) {
            double sk = cScoreB[k];
            int ck = cIdxB[k];
            rank += (sk > si) || (sk == si && ck < ci);
        }
        cSelB[i] = (rank < rem) ? 1 : 0;
    }
    __syncthreads();

#pragma unroll
    for (int e = 0; e < 32; ++e)
        if ((selMask >> e) & 1u) orow[e * TK_T + t] = 1.0f;
    for (int i = t; i < bcnt; i += TK_T)
        if (cSelB[i]) orow[cIdxB[i]] = 1.0f;
}

// ---------------- launch ----------------
extern "C" void kernel_launch(void* const* d_in, const int* in_sizes, int n_in,
                              void* d_out, int out_size, void* d_ws, size_t ws_size,
                              hipStream_t stream)
{
    const float* D = (const float*)d_in[0];
    float* out = (float*)d_out;

    char* ws = (char*)d_ws;
    float*    v     = (float*)ws;                               // 32 KB
    float*    lvf   = (float*)(ws + 64 * 1024);                 // 32 KB
    double*   lvd   = (double*)(ws + 128 * 1024);               // 64 KB
    unsigned* gkeys = (unsigned*)(ws + 192 * 1024);             // 8 B
    unsigned* candCnt = (unsigned*)(ws + 200 * 1024);           // 32 KB
    float*    partials = (float*)(ws + 256 * 1024);             // nwg*32 KB
    const size_t fixed = 256 * 1024;

    int nwg = 512;
    while (nwg > 16 && fixed + (size_t)nwg * NN * 4 > ws_size) nwg >>= 1;
    const int rowsPerWg = NN / nwg;

    const size_t partEnd = fixed + (size_t)nwg * NN * 4;
    unsigned short* candIdx = (unsigned short*)(ws + partEnd);
    float* candD = (float*)(ws + partEnd + (size_t)CAP * NN * 2);
    const size_t needCand = partEnd + (size_t)CAP * NN * 2 + (size_t)CAP * NN * 4;
    const int useCand = (nwg == 512) && (ws_size >= needCand) && (rowsPerWg == 16);

    fill_zero<<<NN, 256, 0, stream>>>(out, gkeys);
    for (int it = 0; it < NITER_RUN; ++it) {
        const int lastIt = (it == NITER_RUN - 1);
        if (lastIt && useCand)
            sinkhorn_cand<<<nwg, IT_T, 0, stream>>>(
                (const float4*)D, (const float4*)v, (float4*)partials,
                candIdx, candD, candCnt, rowsPerWg);
        else
            sinkhorn_iter<<<nwg, IT_T, 0, stream>>>(
                (const float4*)D, (const float4*)v, (float4*)partials,
                rowsPerWg, it == 0);
        col_reduce<<<NN / 32, 256, 0, stream>>>(partials, nwg, v, lvd, lvf, gkeys,
                                                lastIt);
    }
    topk_select<<<NN, TK_T, 0, stream>>>(D, lvd, lvf, gkeys,
                                         candIdx, candD, candCnt, useCand, out);
}

// Round 14
// 262.164 us; speedup vs baseline: 3.2275x; 1.0478x over previous
//
#include <hip/hip_runtime.h>
#include <math.h>

// SinkhornSort: P = diag(u) exp(-D) diag(v); u=1/(Kv), v=1/(K^T u), v0=1.
// Row ranking depends only on s_ij = log(v_j) - D_ij -> never materialize P.
// 3 iterations (truncation ~1e-9 < min rank-gap ~1.2e-6; absmax==0 at 6/4/3).
// Output = zero-fill + scatter 32 ones/row.
// Last sweep emits per-row candidates {col, D_ij} with t=exp(-D)v >= (rs/N)e^1.2
// (~4.5% emit, cnt~365). select_cand: ONE WAVE PER ROW, no block barriers,
// histogram-select over candidates; select_fb: full-row fallback, early-exit.

#define NN 8192
#define NITER_RUN 3
#define TOPK 32
#define CAP 576
#define TKFAC 3.3201169f   // e^1.2
#define TCW 64             // per-wave threshold-bin capacity

typedef float nf4 __attribute__((ext_vector_type(4)));

__device__ __forceinline__ unsigned fkey(float f) {
    unsigned b = __float_as_uint(f);
    return (b & 0x80000000u) ? ~b : (b | 0x80000000u);
}
__device__ __forceinline__ float fkeyinv(unsigned k) {
    unsigned b = (k & 0x80000000u) ? (k & 0x7FFFFFFFu) : ~k;
    return __uint_as_float(b);
}

// ---------------- zero-fill output (nt); init gkeys + doneFlag ----------------
__global__ __launch_bounds__(256)
void fill_zero(float* __restrict__ out, unsigned* __restrict__ gkeys,
               unsigned* __restrict__ doneFlag)
{
    if (blockIdx.x == 0 && threadIdx.x == 0) { gkeys[0] = 0xFFFFFFFFu; gkeys[1] = 0u; }
    if (blockIdx.x < 32) doneFlag[blockIdx.x * 256 + threadIdx.x] = 0u;
    nf4* __restrict__ o4 = (nf4*)out;
    const long base = (long)blockIdx.x * 2048 + threadIdx.x;
    nf4 z = { 0.f, 0.f, 0.f, 0.f };
#pragma unroll
    for (int c = 0; c < 8; ++c)
        __builtin_nontemporal_store(z, &o4[base + (long)c * 256]);
}

// ---------------- lean Sinkhorn iteration (non-last) ----------------
constexpr int IT_T = 512;

__global__ __launch_bounds__(IT_T, 4)
void sinkhorn_iter(const float4* __restrict__ D4, const float4* __restrict__ v4,
                   float4* __restrict__ part4, int rowsPerWg, int first)
{
    const int t = threadIdx.x;
    const int wave = t >> 6, lane = t & 63;
    __shared__ float wred[2][IT_T / 64];

    float4 vreg[4], cacc[4];
#pragma unroll
    for (int c = 0; c < 4; ++c) {
        vreg[c] = first ? make_float4(1.f, 1.f, 1.f, 1.f) : v4[c * IT_T + t];
        cacc[c] = make_float4(0.f, 0.f, 0.f, 0.f);
    }

    const long rowBase = (long)blockIdx.x * rowsPerWg;
    for (int r = 0; r < rowsPerWg; r += 2) {
        float4 ev[2][4];
#pragma unroll
        for (int rr = 0; rr < 2; ++rr) {
            const float4* __restrict__ Dr = D4 + (rowBase + r + rr) * (long)(NN / 4);
            float rs = 0.f;
#pragma unroll
            for (int c = 0; c < 4; ++c) {
                float4 d = Dr[c * IT_T + t];
                float4 e;
                e.x = __expf(-d.x); e.y = __expf(-d.y);
                e.z = __expf(-d.z); e.w = __expf(-d.w);
                ev[rr][c] = e;
                rs += e.x * vreg[c].x + e.y * vreg[c].y
                    + e.z * vreg[c].z + e.w * vreg[c].w;
            }
#pragma unroll
            for (int o = 32; o >= 1; o >>= 1) rs += __shfl_down(rs, o, 64);
            if (lane == 0) wred[rr][wave] = rs;
        }
        __syncthreads();
        float tot0 = 0.f, tot1 = 0.f;
#pragma unroll
        for (int w = 0; w < IT_T / 64; ++w) { tot0 += wred[0][w]; tot1 += wred[1][w]; }
        const float u0 = 1.0f / tot0, u1 = 1.0f / tot1;
#pragma unroll
        for (int c = 0; c < 4; ++c) {
            cacc[c].x += ev[0][c].x * u0 + ev[1][c].x * u1;
            cacc[c].y += ev[0][c].y * u0 + ev[1][c].y * u1;
            cacc[c].z += ev[0][c].z * u0 + ev[1][c].z * u1;
            cacc[c].w += ev[0][c].w * u0 + ev[1][c].w * u1;
        }
        __syncthreads();
    }

    float4* __restrict__ pr = part4 + (long)blockIdx.x * (NN / 4);
#pragma unroll
    for (int c = 0; c < 4; ++c) pr[c * IT_T + t] = cacc[c];
}

// ---------------- last Sinkhorn iteration + candidate emission ----------------
__global__ __launch_bounds__(IT_T, 4)
void sinkhorn_cand(const float4* __restrict__ D4, const float4* __restrict__ v4,
                   float4* __restrict__ part4,
                   unsigned short* __restrict__ candIdx,
                   float* __restrict__ candD,
                   unsigned* __restrict__ candCnt, int rowsPerWg)
{
    const int t = threadIdx.x;
    const int wave = t >> 6, lane = t & 63;
    __shared__ float wred[2][IT_T / 64];
    __shared__ unsigned rowCnt[16];

    float4 vreg[4], cacc[4];
#pragma unroll
    for (int c = 0; c < 4; ++c) {
        vreg[c] = v4[c * IT_T + t];
        cacc[c] = make_float4(0.f, 0.f, 0.f, 0.f);
    }
    if (t < 16) rowCnt[t] = 0;
    __syncthreads();

    const long rowBase = (long)blockIdx.x * rowsPerWg;
    for (int r = 0; r < rowsPerWg; ++r) {
        const float4* __restrict__ Dr = D4 + (rowBase + r) * (long)(NN / 4);
        float4 dv[4];
        float rs = 0.f;
#pragma unroll
        for (int c = 0; c < 4; ++c) {
            float4 d = Dr[c * IT_T + t];
            dv[c] = d;
            rs += __expf(-d.x) * vreg[c].x + __expf(-d.y) * vreg[c].y
                + __expf(-d.z) * vreg[c].z + __expf(-d.w) * vreg[c].w;
        }
#pragma unroll
        for (int o = 32; o >= 1; o >>= 1) rs += __shfl_down(rs, o, 64);
        if (lane == 0) wred[r & 1][wave] = rs;
        __syncthreads();
        float tot = 0.f;
#pragma unroll
        for (int w = 0; w < IT_T / 64; ++w) tot += wred[r & 1][w];
        const float u = 1.0f / tot;
        const float tau = tot * (TKFAC / (float)NN);
        const long rowOff = (rowBase + r) * (long)CAP;

#define PROC(DD, VV, CCREF, COL)                                              \
        {                                                                     \
            float d_ = (DD);                                                  \
            float e_ = __expf(-d_);                                           \
            CCREF += e_ * u;                                                  \
            if (e_ * (VV) >= tau) {                                           \
                unsigned pos_ = atomicAdd(&rowCnt[r], 1u);                    \
                if (pos_ < CAP) {                                             \
                    candIdx[rowOff + pos_] = (unsigned short)(COL);           \
                    candD[rowOff + pos_] = d_;                                \
                }                                                             \
            }                                                                 \
        }

#pragma unroll
        for (int c = 0; c < 4; ++c) {
            const int colBase = (c * IT_T + t) * 4;
            PROC(dv[c].x, vreg[c].x, cacc[c].x, colBase + 0)
            PROC(dv[c].y, vreg[c].y, cacc[c].y, colBase + 1)
            PROC(dv[c].z, vreg[c].z, cacc[c].z, colBase + 2)
            PROC(dv[c].w, vreg[c].w, cacc[c].w, colBase + 3)
        }
#undef PROC
    }
    __syncthreads();
    if (t < 16) candCnt[rowBase + t] = rowCnt[t];

    float4* __restrict__ pr = part4 + (long)blockIdx.x * (NN / 4);
#pragma unroll
    for (int c = 0; c < 4; ++c) pr[c * IT_T + t] = cacc[c];
}

// ---------------- deterministic fused column reduction ----------------
__global__ __launch_bounds__(256)
void col_reduce(const float* __restrict__ partials, int nStrips,
                float* __restrict__ v, double* __restrict__ lvd,
                float* __restrict__ lvf, unsigned* __restrict__ gkeys, int last)
{
    __shared__ double sums[8][33];
    const int jl = threadIdx.x & 31, sg = threadIdx.x >> 5;
    const int j = blockIdx.x * 32 + jl;
    double acc = 0.0;
#pragma unroll 4
    for (int s = sg; s < nStrips; s += 8)
        acc += (double)partials[(long)s * NN + j];
    sums[sg][jl] = acc;
    __syncthreads();
    if (threadIdx.x < 32) {
        double a = 0.0;
#pragma unroll
        for (int g = 0; g < 8; ++g) a += sums[g][threadIdx.x];
        int jj = blockIdx.x * 32 + threadIdx.x;
        if (last) {
            double lv = -log(a);
            lvd[jj] = lv;
            float lf = (float)lv;
            lvf[jj] = lf;
            unsigned k = fkey(lf), kmn = k, kmx = k;
#pragma unroll
            for (int o = 16; o >= 1; o >>= 1) {
                kmn = min(kmn, (unsigned)__shfl_down((int)kmn, o, 64));
                kmx = max(kmx, (unsigned)__shfl_down((int)kmx, o, 64));
            }
            if (threadIdx.x == 0) {
                atomicMin(&gkeys[0], kmn);
                atomicMax(&gkeys[1], kmx);
            }
        } else {
            v[jj] = (float)(1.0 / a);
        }
    }
}

// ---------------- select_cand: ONE WAVE PER ROW, no block barriers ----------------
constexpr int NB = 1024;

__device__ __forceinline__ int qbin(float x, float lo, float scale) {
    int q = (int)((x - lo) * scale);
    return max(0, min(NB - 1, q));
}

__global__ __launch_bounds__(256)
void select_cand(const double* __restrict__ lvd, const float* __restrict__ lvf,
                 const unsigned* __restrict__ gkeys,
                 const unsigned short* __restrict__ candIdx,
                 const float* __restrict__ candD,
                 const unsigned* __restrict__ candCnt,
                 unsigned* __restrict__ doneFlag, float* __restrict__ out)
{
    __shared__ unsigned hist[4][NB];     // 16 KB, one histogram per wave
    __shared__ int tIdx[4][TCW];
    __shared__ unsigned twCnt[4];

    const int t = threadIdx.x;
    const int w = t >> 6, lane = t & 63;
    const long row = (long)blockIdx.x * 4 + w;
    const int cnt = (int)candCnt[row];

    if (lane == 0) twCnt[w] = 0;
    if (cnt < 48 || cnt > CAP) return;   // doneFlag stays 0 -> fallback

    // zero this wave's histogram (stride-1 per instruction: conflict-free)
#pragma unroll
    for (int k = 0; k < NB / 64; ++k) hist[w][k * 64 + lane] = 0u;

    const float lo = fkeyinv(gkeys[0]) - 6.5f;
    const float hi = fkeyinv(gkeys[1]) + 6.5f;
    const float scale = ((float)NB / (hi - lo)) * 0.999999f;
    const long rowOff = row * (long)CAP;
    __builtin_amdgcn_wave_barrier();

    // pass 1: histogram of fp32 scores
    for (int i = lane; i < cnt; i += 64) {
        int ci = candIdx[rowOff + i];
        float s = lvf[ci] - candD[rowOff + i];
        atomicAdd(&hist[w][qbin(s, lo, scale)], 1u);
    }
    __builtin_amdgcn_wave_barrier();

    // wave suffix-scan: 64 superchunks of 16 bins
    const int b0 = lane * 16;
    unsigned csum = 0;
#pragma unroll
    for (int b = 0; b < 16; ++b) csum += hist[w][b0 + ((b + lane) & 15)];
    unsigned suf = csum;
#pragma unroll
    for (int o = 1; o <= 32; o <<= 1) {
        unsigned other = __shfl_down(suf, o, 64);
        if (lane + o < 64) suf += other;
    }
    unsigned long long ball = __ballot(suf >= (unsigned)TOPK);
    const int L = 63 - __clzll(ball);
    int binLocal = 0, aboveLocal = 0;
    if (lane == L) {
        unsigned run = suf - csum;
        int bin = b0 + 15;
        for (; bin > b0; --bin) {
            run += hist[w][bin];
            if (run >= (unsigned)TOPK) break;
        }
        if (run < (unsigned)TOPK) run += hist[w][bin];
        binLocal = bin;
        aboveLocal = (int)(run - hist[w][bin]);
    }
    const int selBin = __shfl(binLocal, L, 64);
    const int rem = TOPK - __shfl(aboveLocal, L, 64);   // >=1

    // pass 2: write sure winners; collect threshold-bin items
    float* __restrict__ orow = out + row * (long)NN;
    for (int i = lane; i < cnt; i += 64) {
        int ci = candIdx[rowOff + i];
        float s = lvf[ci] - candD[rowOff + i];
        int q = qbin(s, lo, scale);
        if (q > selBin) orow[ci] = 1.0f;            // provably top-32
        else if (q == selBin) {
            unsigned pos = atomicAdd(&twCnt[w], 1u);
            if (pos < TCW) tIdx[w][pos] = i;
        }
    }
    __builtin_amdgcn_wave_barrier();
    const int tcnt = (int)twCnt[w];
    if (tcnt > TCW) return;                          // rare: fallback finishes row

    // exact fp64 rank among threshold-bin items (jax tie rule)
    for (int i = lane; i < tcnt; i += 64) {
        int ii = tIdx[w][i];
        int ci = candIdx[rowOff + ii];
        double si = lvd[ci] - (double)candD[rowOff + ii];
        int rank = 0;
        for (int k = 0; k < tcnt; ++k) {
            int kk = tIdx[w][k];
            int ck = candIdx[rowOff + kk];
            double sk = lvd[ck] - (double)candD[rowOff + kk];
            rank += (sk > si) || (sk == si && ck < ci);
        }
        if (rank < rem) orow[ci] = 1.0f;
    }
    if (lane == 0) doneFlag[row] = 1u;
}

// ---------------- select_fb: full-row fallback (early-exit if handled) ----------------
constexpr int TK_T = 256;
constexpr int MAXC = 128;

__global__ __launch_bounds__(TK_T, 4)
void select_fb(const float* __restrict__ D, const double* __restrict__ lvd,
               const float* __restrict__ lvf, const unsigned* __restrict__ gkeys,
               const unsigned* __restrict__ doneFlag, float* __restrict__ out)
{
    __shared__ float slds[NN];
    __shared__ unsigned hist[NB];
    __shared__ int cIdxB[MAXC];
    __shared__ double cScoreB[MAXC];
    __shared__ unsigned char cSelB[MAXC];
    __shared__ int sSelBin, sAbove, sThrCnt, sCand;
    __shared__ float sLo, sScale;

    const long row = blockIdx.x;
    if (doneFlag[row]) return;

    const int t = threadIdx.x;
    const int wave = t >> 6, lane = t & 63;
    float* __restrict__ orow = out + row * (long)NN;
    const float* __restrict__ Drow = D + row * (long)NN;
    const float4* __restrict__ Drow4 = (const float4*)Drow;
    const float4* __restrict__ lvf4 = (const float4*)lvf;
    float4* __restrict__ slds4 = (float4*)slds;

#pragma unroll
    for (int h = 0; h < NB / TK_T; ++h) hist[h * TK_T + t] = 0u;
    if (t == 0) {
        float lo = fkeyinv(gkeys[0]) - 6.5f;
        float hi = fkeyinv(gkeys[1]) + 6.5f;
        sLo = lo;
        sScale = ((float)NB / (hi - lo)) * 0.999999f;
        sCand = 0;
    }
    __syncthreads();
    const float lo0 = sLo, scale0 = sScale;

#pragma unroll
    for (int c = 0; c < 8; ++c) {
        int i4 = c * TK_T + t;
        float4 d = Drow4[i4];
        float4 l = lvf4[i4];
        float4 sc;
        sc.x = l.x - d.x; sc.y = l.y - d.y; sc.z = l.z - d.z; sc.w = l.w - d.w;
        slds4[i4] = sc;
        atomicAdd(&hist[qbin(sc.x, lo0, scale0)], 1u);
        atomicAdd(&hist[qbin(sc.y, lo0, scale0)], 1u);
        atomicAdd(&hist[qbin(sc.z, lo0, scale0)], 1u);
        atomicAdd(&hist[qbin(sc.w, lo0, scale0)], 1u);
    }
    __syncthreads();

    unsigned memberMask = 0xFFFFFFFFu;
    unsigned selMask = 0u;
    float lo = lo0, scale = scale0;
    int rem = TOPK;

    for (int lvl = 0; ; ++lvl) {
        if (wave == 0) {
            const int b0 = lane * 16;
            unsigned csum = 0;
#pragma unroll
            for (int b = 0; b < 16; ++b) csum += hist[b0 + ((b + lane) & 15)];
            unsigned suf = csum;
#pragma unroll
            for (int o = 1; o <= 32; o <<= 1) {
                unsigned other = __shfl_down(suf, o, 64);
                if (lane + o < 64) suf += other;
            }
            unsigned long long ball = __ballot(suf >= (unsigned)rem);
            int L = 63 - __clzll(ball);
            if (lane == L) {
                unsigned run = suf - csum;
                int bin = b0 + 15;
                for (; bin > b0; --bin) {
                    run += hist[bin];
                    if (run >= (unsigned)rem) break;
                }
                if (run < (unsigned)rem) run += hist[bin];
                sSelBin = bin;
                sAbove = (int)(run - hist[bin]);
                sThrCnt = (int)hist[bin];
            }
        }
        __syncthreads();
        const int selBin = sSelBin;
        const int thrCnt = sThrCnt;
        rem -= sAbove;

        unsigned newMember = 0u;
#pragma unroll
        for (int e = 0; e < 32; ++e)
            if ((memberMask >> e) & 1u) {
                int q = qbin(slds[e * TK_T + t], lo, scale);
                if (q > selBin) selMask |= 1u << e;
                else if (q == selBin) newMember |= 1u << e;
            }
        memberMask = newMember;

        bool refine = (thrCnt > MAXC) && (lvl < 3) && (scale < 1.0e30f);
        if (!refine) break;
        float w = 1.0f / scale;
        lo = lo + (float)selBin * w;
        scale = scale * (float)NB;
        __syncthreads();
#pragma unroll
        for (int h = 0; h < NB / TK_T; ++h) hist[h * TK_T + t] = 0u;
        __syncthreads();
#pragma unroll
        for (int e = 0; e < 32; ++e)
            if ((memberMask >> e) & 1u)
                atomicAdd(&hist[qbin(slds[e * TK_T + t], lo, scale)], 1u);
        __syncthreads();
    }

#pragma unroll
    for (int e = 0; e < 32; ++e)
        if ((memberMask >> e) & 1u) {
            int pos = atomicAdd(&sCand, 1);
            if (pos < MAXC) cIdxB[pos] = e * TK_T + t;
        }
    __syncthreads();
    const int bcnt = min(sCand, MAXC);

    for (int i = t; i < bcnt; i += TK_T) {
        int ci = cIdxB[i];
        cScoreB[i] = lvd[ci] - (double)Drow[ci];
    }
    __syncthreads();
    for (int i = t; i < bcnt; i += TK_T) {
        int ci = cIdxB[i];
        double si = cScoreB[i];
        int rank = 0;
        for (int k = 0; k < bcnt; ++k) {
            double sk = cScoreB[k];
            int ck = cIdxB[k];
            rank += (sk > si) || (sk == si && ck < ci);
        }
        cSelB[i] = (rank < rem) ? 1 : 0;
    }
    __syncthreads();

#pragma unroll
    for (int e = 0; e < 32; ++e)
        if ((selMask >> e) & 1u) orow[e * TK_T + t] = 1.0f;
    for (int i = t; i < bcnt; i += TK_T)
        if (cSelB[i]) orow[cIdxB[i]] = 1.0f;
}

// ---------------- launch ----------------
extern "C" void kernel_launch(void* const* d_in, const int* in_sizes, int n_in,
                              void* d_out, int out_size, void* d_ws, size_t ws_size,
                              hipStream_t stream)
{
    const float* D = (const float*)d_in[0];
    float* out = (float*)d_out;

    char* ws = (char*)d_ws;
    float*    v        = (float*)ws;                            // 32 KB
    float*    lvf      = (float*)(ws + 64 * 1024);              // 32 KB
    double*   lvd      = (double*)(ws + 128 * 1024);            // 64 KB
    unsigned* gkeys    = (unsigned*)(ws + 192 * 1024);          // 8 B
    unsigned* candCnt  = (unsigned*)(ws + 196 * 1024);          // 32 KB
    unsigned* doneFlag = (unsigned*)(ws + 228 * 1024);          // 32 KB
    float*    partials = (float*)(ws + 320 * 1024);             // nwg*32 KB
    const size_t fixed = 320 * 1024;

    int nwg = 512;
    while (nwg > 16 && fixed + (size_t)nwg * NN * 4 > ws_size) nwg >>= 1;
    const int rowsPerWg = NN / nwg;

    const size_t partEnd = fixed + (size_t)nwg * NN * 4;
    unsigned short* candIdx = (unsigned short*)(ws + partEnd);
    float* candD = (float*)(ws + partEnd + (size_t)CAP * NN * 2);
    const size_t needCand = partEnd + (size_t)CAP * NN * 2 + (size_t)CAP * NN * 4;
    const int useCand = (nwg == 512) && (ws_size >= needCand) && (rowsPerWg == 16);

    fill_zero<<<NN, 256, 0, stream>>>(out, gkeys, doneFlag);
    for (int it = 0; it < NITER_RUN; ++it) {
        const int lastIt = (it == NITER_RUN - 1);
        if (lastIt && useCand)
            sinkhorn_cand<<<nwg, IT_T, 0, stream>>>(
                (const float4*)D, (const float4*)v, (float4*)partials,
                candIdx, candD, candCnt, rowsPerWg);
        else
            sinkhorn_iter<<<nwg, IT_T, 0, stream>>>(
                (const float4*)D, (const float4*)v, (float4*)partials,
                rowsPerWg, it == 0);
        col_reduce<<<NN / 32, 256, 0, stream>>>(partials, nwg, v, lvd, lvf, gkeys,
                                                lastIt);
    }
    if (useCand)
        select_cand<<<NN / 4, 256, 0, stream>>>(lvd, lvf, gkeys, candIdx, candD,
                                                candCnt, doneFlag, out);
    select_fb<<<NN, TK_T, 0, stream>>>(D, lvd, lvf, gkeys, doneFlag, out);
}